// Round 14
// baseline (39.554 us; speedup 1.0000x reference)
//
#include <hip/hip_runtime.h>

#define EDGE_K 32
#define CAP    128   // per-node candidate cap before serial fallback
#define NB     64    // graph-bounds table entries (graph ids must be < NB-1)
#define DEPTH  8     // software-pipeline depth (chunks in flight)
#define WPB    4     // independent waves (nodes) per block — NO inter-wave sync

__device__ __forceinline__ int prefix_count(unsigned long long mask) {
    return (int)__builtin_amdgcn_mbcnt_hi((unsigned)(mask >> 32),
                __builtin_amdgcn_mbcnt_lo((unsigned)mask, 0u));
}

// --- pack positions to float4 AND emit graph boundary table (race-free:
// each bounds[g] is written by exactly one thread).
__global__ __launch_bounds__(256) void pack_kernel(
    const float* __restrict__ pos, const int* __restrict__ n2g,
    float4* __restrict__ pk, int* __restrict__ bounds, int n)
{
    int i = blockIdx.x * blockDim.x + threadIdx.x;
    if (i >= n) return;
    pk[i] = make_float4(pos[3*i+0], pos[3*i+1], pos[3*i+2], 0.0f);
    const int gi = n2g[i];
    if (i == 0) {
        for (int g = 0; g <= gi && g < NB; ++g) bounds[g] = 0;
    } else {
        const int gp = n2g[i-1];
        if (gp != gi) for (int g = gp + 1; g <= gi && g < NB; ++g) bounds[g] = i;
    }
    if (i == n - 1) {
        for (int g = gi + 1; g < NB; ++g) bounds[g] = n;
    }
}

// --- fast path: WPB independent waves per block, one node per wave.
// Per-wave program is byte-identical to the passing R13 kernel; the only
// changes are (a) i = blockIdx*WPB + wave, (b) per-wave LDS slices,
// (c) __syncthreads -> __threadfence_block (same-wave LDS ordering only;
// waves never read each other's LDS, so no inter-wave barrier is needed).
__global__ __launch_bounds__(WPB * 64) void spatial_edge_fast(
    const float4* __restrict__ pk,
    const int* __restrict__ n2g,
    const int* __restrict__ a2r,
    const int* __restrict__ bounds,
    int* __restrict__ out, int n)
{
    const int wave = threadIdx.x >> 6;
    const int lane = threadIdx.x & 63;
    const int i    = blockIdx.x * WPB + wave;
    if (i >= n) return;                       // whole-wave exit; no barriers below

    __shared__ int2 scand[WPB][CAP];
    __shared__ int2 sres[WPB][EDGE_K];
    __shared__ int2 ebuf2[WPB][EDGE_K * 3 / 2];   // 96 dwords per wave

    const float4 pi = pk[i];
    const float xi = pi.x, yi = pi.y, zi = pi.z;
    const float si = xi*xi + yi*yi + zi*zi;
    const int g  = n2g[i];
    const int ri = a2r[i];

    int jstart, jend;
    if (g < NB - 1) {
        jstart = bounds[g];
        jend   = bounds[g + 1];
    } else {  // defensive: graph id outside table -> binary search
        int lo = 0, hi = n;
        while (lo < hi) { int m = (lo + hi) >> 1; if (n2g[m] < g) lo = m + 1; else hi = m; }
        jstart = lo; hi = n;
        while (lo < hi) { int m = (lo + hi) >> 1; if (n2g[m] <= g) lo = m + 1; else hi = m; }
        jend = lo;
    }

    int count = 0;
    auto process = [&](float4 p, int j) {
        bool pass = false; float d2 = 0.0f;
        if (j < jend && j != i) {
            const float sj2 = p.x*p.x + p.y*p.y + p.z*p.z;
            const float dt  = xi*p.x + yi*p.y + zi*p.z;
            d2 = si + sj2 - 2.0f*dt;          // exact reference formula
            d2 = fmaxf(d2, 0.0f);
            pass = (d2 <= 25.0f);
        }
        const unsigned long long mask = __ballot(pass);
        if (pass) {
            const int idx = count + prefix_count(mask);
            if (idx < CAP) scand[wave][idx] = make_int2(__float_as_int(d2), j);
        }
        count += __popcll(mask);
    };

    const int nch  = (jend - jstart + 63) >> 6;
    const int jm   = jend - 1;
    const int base = jstart + lane;

    float4 buf[DEPTH];
#pragma unroll
    for (int u = 0; u < DEPTH; ++u)
        buf[u] = pk[min(base + (u << 6), jm)];          // clamped, branch-free

    for (int c = 0; c < nch; c += DEPTH) {
        // issue NEXT group's loads before processing current (double-buffer)
        float4 nxt[DEPTH];
        const int nb = base + ((c + DEPTH) << 6);
#pragma unroll
        for (int u = 0; u < DEPTH; ++u)
            nxt[u] = pk[min(nb + (u << 6), jm)];        // clamped: safe over-read
        const int ja = jstart + (c << 6) + lane;
#pragma unroll
        for (int u = 0; u < DEPTH; ++u) {
            if (c + u < nch) process(buf[u], ja + (u << 6));
        }
#pragma unroll
        for (int u = 0; u < DEPTH; ++u) buf[u] = nxt[u];
    }
    __threadfence_block();   // order this wave's scand writes before its reads

    int cnt = 0;
    if (count <= CAP) {
        // rank-based stable sort: rank = #{(d2',j') < (d2,j)} lexicographic
        const int m = count;
        for (int c = lane; c < m; c += 64) {
            const int2 e = scand[wave][c];
            const float dc = __int_as_float(e.x);
            int rank = 0;
            for (int t = 0; t < m; ++t) {
                const int2 et = scand[wave][t];
                const float dtv = __int_as_float(et.x);
                rank += (dtv < dc) || (dtv == dc && et.y < e.y);
            }
            if (rank < EDGE_K) sres[wave][rank] = e;
        }
        cnt = (m < EDGE_K) ? m : EDGE_K;
    } else {
        // serial fallback (astronomically rare): lane 0 insertion top-K
        if (lane == 0) {
            float bd[EDGE_K]; int bj[EDGE_K]; int c2 = 0;
            for (int j = jstart; j < jend; ++j) {
                if (j == i) continue;
                const float4 p = pk[j];
                const float sj2 = p.x*p.x + p.y*p.y + p.z*p.z;
                const float dt  = xi*p.x + yi*p.y + zi*p.z;
                float d2 = si + sj2 - 2.0f*dt;
                d2 = fmaxf(d2, 0.0f);
                if (d2 > 25.0f) continue;
                if (c2 == EDGE_K && d2 >= bd[EDGE_K-1]) continue;
                int p2 = (c2 < EDGE_K) ? c2 : (EDGE_K - 1);
                while (p2 > 0 && bd[p2-1] > d2) { bd[p2] = bd[p2-1]; bj[p2] = bj[p2-1]; --p2; }
                bd[p2] = d2; bj[p2] = j;
                if (c2 < EDGE_K) ++c2;
            }
            for (int k = 0; k < c2; ++k) sres[wave][k] = make_int2(__float_as_int(bd[k]), bj[k]);
        }
        cnt = (count < EDGE_K) ? count : EDGE_K;
    }
    __threadfence_block();   // order this wave's sres writes before its reads

    const int NK = n * EDGE_K;
    int* valid_out = out + 3 * NK;
    int* eb = (int*)&ebuf2[wave][0];
    if (lane < EDGE_K) {
        const int k = lane;
        int a = -1, b = -1, c = -1, v = 0;
        if (k < cnt) {
            const int j = sres[wave][k].y;
            const int rj = a2r[j];
            const int rd = (rj > ri) ? (rj - ri) : (ri - rj);
            const float4 p = pk[j];
            const float dx = p.x - xi, dy = p.y - yi, dz = p.z - zi;
            const float d2s = dx*dx + dy*dy + dz*dz;
            if (rd >= 5 && d2s >= 1e-20f) { a = j; b = i; c = 0; v = 1; }
        }
        eb[3*k+0] = a;
        eb[3*k+1] = b;
        eb[3*k+2] = c;
        valid_out[i * EDGE_K + k] = v;    // 32 contiguous dwords: coalesced
    }
    __threadfence_block();   // order this wave's ebuf writes before its reads
    // coalesced edge write: 96 dwords as 48 contiguous int2 stores
    if (lane < 48) {
        int2* eo = (int2*)(out + 3 * (i * EDGE_K));
        eo[lane] = ebuf2[wave][lane];
    }
    if (i == 0 && lane == 0) out[4*NK] = 1;   // the jnp.int32(1) scalar output
}

// --- fallback path (ws too small): exact round-2 structure, known-correct
__global__ __launch_bounds__(64) void spatial_edge_ref(
    const float* __restrict__ pos,
    const int* __restrict__ n2g,
    const int* __restrict__ a2r,
    int* __restrict__ out, int n)
{
    const int i = blockIdx.x;
    const int lane = threadIdx.x;
    __shared__ float sd2[CAP]; __shared__ int sj[CAP];
    __shared__ float rd2[EDGE_K]; __shared__ int rjj[EDGE_K];

    const float xi = pos[3*i+0], yi = pos[3*i+1], zi = pos[3*i+2];
    const float si = xi*xi + yi*yi + zi*zi;
    const int g = n2g[i]; const int ri = a2r[i];

    int lo = 0, hi = n;
    while (lo < hi) { int m = (lo + hi) >> 1; if (n2g[m] < g) lo = m + 1; else hi = m; }
    const int jstart = lo; hi = n;
    while (lo < hi) { int m = (lo + hi) >> 1; if (n2g[m] <= g) lo = m + 1; else hi = m; }
    const int jend = lo;

    int count = 0;
    for (int j0 = jstart; j0 < jend; j0 += 64) {
        const int j = j0 + lane;
        bool pass = false; float d2 = 0.0f;
        if (j < jend && j != i) {
            const float xj = pos[3*j+0], yj = pos[3*j+1], zj = pos[3*j+2];
            const float sj2 = xj*xj + yj*yj + zj*zj;
            const float dt  = xi*xj + yi*yj + zi*zj;
            d2 = fmaxf(si + sj2 - 2.0f*dt, 0.0f);
            pass = (d2 <= 25.0f);
        }
        const unsigned long long mask = __ballot(pass);
        if (pass) {
            const int idx = count + prefix_count(mask);
            if (idx < CAP) { sd2[idx] = d2; sj[idx] = j; }
        }
        count += __popcll(mask);
    }
    __syncthreads();

    int cnt;
    if (count <= CAP) {
        const int m = count;
        for (int c = lane; c < m; c += 64) {
            const float dc = sd2[c]; const int jc = sj[c];
            int rank = 0;
            for (int t = 0; t < m; ++t)
                rank += (sd2[t] < dc) || (sd2[t] == dc && sj[t] < jc);
            if (rank < EDGE_K) { rd2[rank] = dc; rjj[rank] = jc; }
        }
        cnt = (m < EDGE_K) ? m : EDGE_K;
    } else {
        if (lane == 0) {
            float bd[EDGE_K]; int bj[EDGE_K]; int c2 = 0;
            for (int j = jstart; j < jend; ++j) {
                if (j == i) continue;
                const float xj = pos[3*j+0], yj = pos[3*j+1], zj = pos[3*j+2];
                const float sj2 = xj*xj + yj*yj + zj*zj;
                const float dt  = xi*xj + yi*yj + zi*zj;
                float d2 = fmaxf(si + sj2 - 2.0f*dt, 0.0f);
                if (d2 > 25.0f) continue;
                if (c2 == EDGE_K && d2 >= bd[EDGE_K-1]) continue;
                int p = (c2 < EDGE_K) ? c2 : (EDGE_K - 1);
                while (p > 0 && bd[p-1] > d2) { bd[p] = bd[p-1]; bj[p] = bj[p-1]; --p; }
                bd[p] = d2; bj[p] = j;
                if (c2 < EDGE_K) ++c2;
            }
            for (int k = 0; k < c2; ++k) { rd2[k] = bd[k]; rjj[k] = bj[k]; }
        }
        cnt = (count < EDGE_K) ? count : EDGE_K;
    }
    __syncthreads();

    const int NK = n * EDGE_K;
    int* valid_out = out + 3 * NK;
    if (lane < EDGE_K) {
        const int k = lane;
        int a = -1, b = -1, c = -1, v = 0;
        if (k < cnt) {
            const int j = rjj[k];
            const int rj = a2r[j];
            const int rd = (rj > ri) ? (rj - ri) : (ri - rj);
            const float dx = pos[3*j+0] - xi, dy = pos[3*j+1] - yi, dz = pos[3*j+2] - zi;
            const float d2s = dx*dx + dy*dy + dz*dz;
            if (rd >= 5 && d2s >= 1e-20f) { a = j; b = i; c = 0; v = 1; }
        }
        const int e = i * EDGE_K + k;
        out[3*e+0] = a; out[3*e+1] = b; out[3*e+2] = c;
        valid_out[e] = v;
    }
    if (i == 0 && lane == 0) out[4*NK] = 1;
}

extern "C" void kernel_launch(void* const* d_in, const int* in_sizes, int n_in,
                              void* d_out, int out_size, void* d_ws, size_t ws_size,
                              hipStream_t stream) {
    const float* pos = (const float*)d_in[0];
    const int*   n2g = (const int*)d_in[1];
    const int*   a2r = (const int*)d_in[2];
    int* out = (int*)d_out;
    const int n = in_sizes[0] / 3;
    const size_t need = (size_t)n * sizeof(float4) + NB * sizeof(int);
    const bool packed = (ws_size >= need) && (((uintptr_t)d_ws & 15) == 0);
    if (packed) {
        float4* pk = (float4*)d_ws;
        int* bounds = (int*)(pk + n);
        hipLaunchKernelGGL(pack_kernel, dim3((n + 255) / 256), dim3(256), 0, stream,
                           pos, n2g, pk, bounds, n);
        const int grid = (n + WPB - 1) / WPB;
        hipLaunchKernelGGL(spatial_edge_fast, dim3(grid), dim3(WPB * 64), 0, stream,
                           (const float4*)pk, n2g, a2r, (const int*)bounds, out, n);
    } else {
        hipLaunchKernelGGL(spatial_edge_ref, dim3(n), dim3(64), 0, stream,
                           pos, n2g, a2r, out, n);
    }
}

// Round 15
// 29.238 us; speedup vs baseline: 1.3528x; 1.3528x over previous
//
#include <hip/hip_runtime.h>

#define EDGE_K 32
#define CAP    128   // per-node candidate cap before serial fallback
#define NB     64    // graph-bounds table entries (graph ids must be < NB-1)
#define DEPTH  8     // software-pipeline depth (chunks in flight)

__device__ __forceinline__ int prefix_count(unsigned long long mask) {
    return (int)__builtin_amdgcn_mbcnt_hi((unsigned)(mask >> 32),
                __builtin_amdgcn_mbcnt_lo((unsigned)mask, 0u));
}

// --- pack positions to float4 AND emit graph boundary table (race-free:
// each bounds[g] is written by exactly one thread).
__global__ __launch_bounds__(256) void pack_kernel(
    const float* __restrict__ pos, const int* __restrict__ n2g,
    float4* __restrict__ pk, int* __restrict__ bounds, int n)
{
    int i = blockIdx.x * blockDim.x + threadIdx.x;
    if (i >= n) return;
    pk[i] = make_float4(pos[3*i+0], pos[3*i+1], pos[3*i+2], 0.0f);
    const int gi = n2g[i];
    if (i == 0) {
        for (int g = 0; g <= gi && g < NB; ++g) bounds[g] = 0;
    } else {
        const int gp = n2g[i-1];
        if (gp != gi) for (int g = gp + 1; g <= gi && g < NB; ++g) bounds[g] = i;
    }
    if (i == n - 1) {
        for (int g = gi + 1; g < NB; ++g) bounds[g] = n;
    }
}

// --- fast path: one wave per node; 8-deep double-buffered load pipeline.
// process() body and call order are byte-identical to the passing R8 kernel.
__global__ __launch_bounds__(64) void spatial_edge_fast(
    const float4* __restrict__ pk,
    const int* __restrict__ n2g,
    const int* __restrict__ a2r,
    const int* __restrict__ bounds,
    int* __restrict__ out, int n)
{
    const int i    = blockIdx.x;
    const int lane = threadIdx.x;

    __shared__ int2 scand[CAP];
    __shared__ int2 sres[EDGE_K];
    __shared__ int2 ebuf2[EDGE_K * 3 / 2];   // 96 dwords, 8B-aligned

    const float4 pi = pk[i];
    const float xi = pi.x, yi = pi.y, zi = pi.z;
    const float si = xi*xi + yi*yi + zi*zi;
    const int g  = n2g[i];
    const int ri = a2r[i];

    int jstart, jend;
    if (g < NB - 1) {
        jstart = bounds[g];
        jend   = bounds[g + 1];
    } else {  // defensive: graph id outside table -> binary search
        int lo = 0, hi = n;
        while (lo < hi) { int m = (lo + hi) >> 1; if (n2g[m] < g) lo = m + 1; else hi = m; }
        jstart = lo; hi = n;
        while (lo < hi) { int m = (lo + hi) >> 1; if (n2g[m] <= g) lo = m + 1; else hi = m; }
        jend = lo;
    }

    int count = 0;
    auto process = [&](float4 p, int j) {
        bool pass = false; float d2 = 0.0f;
        if (j < jend && j != i) {
            const float sj2 = p.x*p.x + p.y*p.y + p.z*p.z;
            const float dt  = xi*p.x + yi*p.y + zi*p.z;
            d2 = si + sj2 - 2.0f*dt;          // exact reference formula
            d2 = fmaxf(d2, 0.0f);
            pass = (d2 <= 25.0f);
        }
        const unsigned long long mask = __ballot(pass);
        if (pass) {
            const int idx = count + prefix_count(mask);
            if (idx < CAP) scand[idx] = make_int2(__float_as_int(d2), j);
        }
        count += __popcll(mask);
    };

    const int nch  = (jend - jstart + 63) >> 6;
    const int jm   = jend - 1;
    const int base = jstart + lane;

    float4 buf[DEPTH];
#pragma unroll
    for (int u = 0; u < DEPTH; ++u)
        buf[u] = pk[min(base + (u << 6), jm)];          // clamped, branch-free

    for (int c = 0; c < nch; c += DEPTH) {
        // issue NEXT group's loads before processing current (double-buffer)
        float4 nxt[DEPTH];
        const int nb = base + ((c + DEPTH) << 6);
#pragma unroll
        for (int u = 0; u < DEPTH; ++u)
            nxt[u] = pk[min(nb + (u << 6), jm)];        // clamped: safe over-read
        const int ja = jstart + (c << 6) + lane;
#pragma unroll
        for (int u = 0; u < DEPTH; ++u) {
            if (c + u < nch) process(buf[u], ja + (u << 6));
        }
#pragma unroll
        for (int u = 0; u < DEPTH; ++u) buf[u] = nxt[u];
    }
    __syncthreads();

    int cnt = 0;
    if (count <= CAP) {
        // rank-based stable sort: rank = #{(d2',j') < (d2,j)} lexicographic
        const int m = count;
        for (int c = lane; c < m; c += 64) {
            const int2 e = scand[c];
            const float dc = __int_as_float(e.x);
            int rank = 0;
            for (int t = 0; t < m; ++t) {
                const int2 et = scand[t];
                const float dtv = __int_as_float(et.x);
                rank += (dtv < dc) || (dtv == dc && et.y < e.y);
            }
            if (rank < EDGE_K) sres[rank] = e;
        }
        cnt = (m < EDGE_K) ? m : EDGE_K;
    } else {
        // serial fallback (astronomically rare): lane 0 insertion top-K
        if (lane == 0) {
            float bd[EDGE_K]; int bj[EDGE_K]; int c2 = 0;
            for (int j = jstart; j < jend; ++j) {
                if (j == i) continue;
                const float4 p = pk[j];
                const float sj2 = p.x*p.x + p.y*p.y + p.z*p.z;
                const float dt  = xi*p.x + yi*p.y + zi*p.z;
                float d2 = si + sj2 - 2.0f*dt;
                d2 = fmaxf(d2, 0.0f);
                if (d2 > 25.0f) continue;
                if (c2 == EDGE_K && d2 >= bd[EDGE_K-1]) continue;
                int p2 = (c2 < EDGE_K) ? c2 : (EDGE_K - 1);
                while (p2 > 0 && bd[p2-1] > d2) { bd[p2] = bd[p2-1]; bj[p2] = bj[p2-1]; --p2; }
                bd[p2] = d2; bj[p2] = j;
                if (c2 < EDGE_K) ++c2;
            }
            for (int k = 0; k < c2; ++k) sres[k] = make_int2(__float_as_int(bd[k]), bj[k]);
        }
        cnt = (count < EDGE_K) ? count : EDGE_K;
    }
    __syncthreads();

    const int NK = n * EDGE_K;
    int* valid_out = out + 3 * NK;
    int* eb = (int*)ebuf2;
    if (lane < EDGE_K) {
        const int k = lane;
        int a = -1, b = -1, c = -1, v = 0;
        if (k < cnt) {
            const int j = sres[k].y;
            const int rj = a2r[j];
            const int rd = (rj > ri) ? (rj - ri) : (ri - rj);
            const float4 p = pk[j];
            const float dx = p.x - xi, dy = p.y - yi, dz = p.z - zi;
            const float d2s = dx*dx + dy*dy + dz*dz;
            if (rd >= 5 && d2s >= 1e-20f) { a = j; b = i; c = 0; v = 1; }
        }
        eb[3*k+0] = a;
        eb[3*k+1] = b;
        eb[3*k+2] = c;
        valid_out[i * EDGE_K + k] = v;    // 32 contiguous dwords: coalesced
    }
    __syncthreads();
    // coalesced edge write: 96 dwords as 48 contiguous int2 stores
    if (lane < 48) {
        int2* eo = (int2*)(out + 3 * (i * EDGE_K));
        eo[lane] = ebuf2[lane];
    }
    if (i == 0 && lane == 0) out[4*NK] = 1;   // the jnp.int32(1) scalar output
}

// --- fallback path (ws too small): exact round-2 structure, known-correct
__global__ __launch_bounds__(64) void spatial_edge_ref(
    const float* __restrict__ pos,
    const int* __restrict__ n2g,
    const int* __restrict__ a2r,
    int* __restrict__ out, int n)
{
    const int i = blockIdx.x;
    const int lane = threadIdx.x;
    __shared__ float sd2[CAP]; __shared__ int sj[CAP];
    __shared__ float rd2[EDGE_K]; __shared__ int rjj[EDGE_K];

    const float xi = pos[3*i+0], yi = pos[3*i+1], zi = pos[3*i+2];
    const float si = xi*xi + yi*yi + zi*zi;
    const int g = n2g[i]; const int ri = a2r[i];

    int lo = 0, hi = n;
    while (lo < hi) { int m = (lo + hi) >> 1; if (n2g[m] < g) lo = m + 1; else hi = m; }
    const int jstart = lo; hi = n;
    while (lo < hi) { int m = (lo + hi) >> 1; if (n2g[m] <= g) lo = m + 1; else hi = m; }
    const int jend = lo;

    int count = 0;
    for (int j0 = jstart; j0 < jend; j0 += 64) {
        const int j = j0 + lane;
        bool pass = false; float d2 = 0.0f;
        if (j < jend && j != i) {
            const float xj = pos[3*j+0], yj = pos[3*j+1], zj = pos[3*j+2];
            const float sj2 = xj*xj + yj*yj + zj*zj;
            const float dt  = xi*xj + yi*yj + zi*zj;
            d2 = fmaxf(si + sj2 - 2.0f*dt, 0.0f);
            pass = (d2 <= 25.0f);
        }
        const unsigned long long mask = __ballot(pass);
        if (pass) {
            const int idx = count + prefix_count(mask);
            if (idx < CAP) { sd2[idx] = d2; sj[idx] = j; }
        }
        count += __popcll(mask);
    }
    __syncthreads();

    int cnt;
    if (count <= CAP) {
        const int m = count;
        for (int c = lane; c < m; c += 64) {
            const float dc = sd2[c]; const int jc = sj[c];
            int rank = 0;
            for (int t = 0; t < m; ++t)
                rank += (sd2[t] < dc) || (sd2[t] == dc && sj[t] < jc);
            if (rank < EDGE_K) { rd2[rank] = dc; rjj[rank] = jc; }
        }
        cnt = (m < EDGE_K) ? m : EDGE_K;
    } else {
        if (lane == 0) {
            float bd[EDGE_K]; int bj[EDGE_K]; int c2 = 0;
            for (int j = jstart; j < jend; ++j) {
                if (j == i) continue;
                const float xj = pos[3*j+0], yj = pos[3*j+1], zj = pos[3*j+2];
                const float sj2 = xj*xj + yj*yj + zj*zj;
                const float dt  = xi*xj + yi*yj + zi*zj;
                float d2 = fmaxf(si + sj2 - 2.0f*dt, 0.0f);
                if (d2 > 25.0f) continue;
                if (c2 == EDGE_K && d2 >= bd[EDGE_K-1]) continue;
                int p = (c2 < EDGE_K) ? c2 : (EDGE_K - 1);
                while (p > 0 && bd[p-1] > d2) { bd[p] = bd[p-1]; bj[p] = bj[p-1]; --p; }
                bd[p] = d2; bj[p] = j;
                if (c2 < EDGE_K) ++c2;
            }
            for (int k = 0; k < c2; ++k) { rd2[k] = bd[k]; rjj[k] = bj[k]; }
        }
        cnt = (count < EDGE_K) ? count : EDGE_K;
    }
    __syncthreads();

    const int NK = n * EDGE_K;
    int* valid_out = out + 3 * NK;
    if (lane < EDGE_K) {
        const int k = lane;
        int a = -1, b = -1, c = -1, v = 0;
        if (k < cnt) {
            const int j = rjj[k];
            const int rj = a2r[j];
            const int rd = (rj > ri) ? (rj - ri) : (ri - rj);
            const float dx = pos[3*j+0] - xi, dy = pos[3*j+1] - yi, dz = pos[3*j+2] - zi;
            const float d2s = dx*dx + dy*dy + dz*dz;
            if (rd >= 5 && d2s >= 1e-20f) { a = j; b = i; c = 0; v = 1; }
        }
        const int e = i * EDGE_K + k;
        out[3*e+0] = a; out[3*e+1] = b; out[3*e+2] = c;
        valid_out[e] = v;
    }
    if (i == 0 && lane == 0) out[4*NK] = 1;
}

extern "C" void kernel_launch(void* const* d_in, const int* in_sizes, int n_in,
                              void* d_out, int out_size, void* d_ws, size_t ws_size,
                              hipStream_t stream) {
    const float* pos = (const float*)d_in[0];
    const int*   n2g = (const int*)d_in[1];
    const int*   a2r = (const int*)d_in[2];
    int* out = (int*)d_out;
    const int n = in_sizes[0] / 3;
    const size_t need = (size_t)n * sizeof(float4) + NB * sizeof(int);
    const bool packed = (ws_size >= need) && (((uintptr_t)d_ws & 15) == 0);
    if (packed) {
        float4* pk = (float4*)d_ws;
        int* bounds = (int*)(pk + n);
        hipLaunchKernelGGL(pack_kernel, dim3((n + 255) / 256), dim3(256), 0, stream,
                           pos, n2g, pk, bounds, n);
        hipLaunchKernelGGL(spatial_edge_fast, dim3(n), dim3(64), 0, stream,
                           (const float4*)pk, n2g, a2r, (const int*)bounds, out, n);
    } else {
        hipLaunchKernelGGL(spatial_edge_ref, dim3(n), dim3(64), 0, stream,
                           pos, n2g, a2r, out, n);
    }
}

// Round 16
// 28.665 us; speedup vs baseline: 1.3799x; 1.0200x over previous
//
#include <hip/hip_runtime.h>

#define EDGE_K 32
#define CAP    128   // per-node candidate cap before serial fallback
#define DEPTH  8     // software-pipeline depth (chunks in flight)

__device__ __forceinline__ int prefix_count(unsigned long long mask) {
    return (int)__builtin_amdgcn_mbcnt_hi((unsigned)(mask >> 32),
                __builtin_amdgcn_mbcnt_lo((unsigned)mask, 0u));
}

// --- pack positions to float4 with the node's same-graph range bit-packed
// into w (js<<14 | je; both <= 12288 < 2^14). Each thread does its own
// binary search over the sorted n2g — fully parallel, latency-hidden.
// Plain loads/stores are bit-preserving, and w is never touched by FP ops.
__global__ __launch_bounds__(256) void pack_kernel(
    const float* __restrict__ pos, const int* __restrict__ n2g,
    float4* __restrict__ pk, int n)
{
    int i = blockIdx.x * blockDim.x + threadIdx.x;
    if (i >= n) return;
    const int g = n2g[i];
    int lo = 0, hi = n;
    while (lo < hi) { int m = (lo + hi) >> 1; if (n2g[m] < g) lo = m + 1; else hi = m; }
    const int js = lo;
    hi = n;
    while (lo < hi) { int m = (lo + hi) >> 1; if (n2g[m] <= g) lo = m + 1; else hi = m; }
    const int je = lo;
    const unsigned pr = ((unsigned)js << 14) | (unsigned)je;
    pk[i] = make_float4(pos[3*i+0], pos[3*i+1], pos[3*i+2], __uint_as_float(pr));
}

// --- fast path: one wave per node; single-load prologue (position + range
// in one dwordx4); 8-deep double-buffered load pipeline. process() body,
// scan order, sort and epilogue are byte-identical to the R13/R15 anchor.
__global__ __launch_bounds__(64) void spatial_edge_fast(
    const float4* __restrict__ pk,
    const int* __restrict__ a2r,
    int* __restrict__ out, int n)
{
    const int i    = blockIdx.x;
    const int lane = threadIdx.x;

    __shared__ int2 scand[CAP];
    __shared__ int2 sres[EDGE_K];
    __shared__ int2 ebuf2[EDGE_K * 3 / 2];   // 96 dwords, 8B-aligned

    const float4 pi = pk[i];
    const float xi = pi.x, yi = pi.y, zi = pi.z;
    const float si = xi*xi + yi*yi + zi*zi;
    const unsigned pr = __float_as_uint(pi.w);
    const int jstart = (int)(pr >> 14);
    const int jend   = (int)(pr & 0x3FFFu);
    const int ri = a2r[i];     // independent load; overlaps the scan

    int count = 0;
    auto process = [&](float4 p, int j) {
        bool pass = false; float d2 = 0.0f;
        if (j < jend && j != i) {
            const float sj2 = p.x*p.x + p.y*p.y + p.z*p.z;
            const float dt  = xi*p.x + yi*p.y + zi*p.z;
            d2 = si + sj2 - 2.0f*dt;          // exact reference formula
            d2 = fmaxf(d2, 0.0f);
            pass = (d2 <= 25.0f);
        }
        const unsigned long long mask = __ballot(pass);
        if (pass) {
            const int idx = count + prefix_count(mask);
            if (idx < CAP) scand[idx] = make_int2(__float_as_int(d2), j);
        }
        count += __popcll(mask);
    };

    const int nch  = (jend - jstart + 63) >> 6;
    const int jm   = jend - 1;
    const int base = jstart + lane;

    float4 buf[DEPTH];
#pragma unroll
    for (int u = 0; u < DEPTH; ++u)
        buf[u] = pk[min(base + (u << 6), jm)];          // clamped, branch-free

    for (int c = 0; c < nch; c += DEPTH) {
        // issue NEXT group's loads before processing current (double-buffer)
        float4 nxt[DEPTH];
        const int nb = base + ((c + DEPTH) << 6);
#pragma unroll
        for (int u = 0; u < DEPTH; ++u)
            nxt[u] = pk[min(nb + (u << 6), jm)];        // clamped: safe over-read
        const int ja = jstart + (c << 6) + lane;
#pragma unroll
        for (int u = 0; u < DEPTH; ++u) {
            if (c + u < nch) process(buf[u], ja + (u << 6));
        }
#pragma unroll
        for (int u = 0; u < DEPTH; ++u) buf[u] = nxt[u];
    }
    __syncthreads();

    int cnt = 0;
    if (count <= CAP) {
        // rank-based stable sort: rank = #{(d2',j') < (d2,j)} lexicographic
        const int m = count;
        for (int c = lane; c < m; c += 64) {
            const int2 e = scand[c];
            const float dc = __int_as_float(e.x);
            int rank = 0;
            for (int t = 0; t < m; ++t) {
                const int2 et = scand[t];
                const float dtv = __int_as_float(et.x);
                rank += (dtv < dc) || (dtv == dc && et.y < e.y);
            }
            if (rank < EDGE_K) sres[rank] = e;
        }
        cnt = (m < EDGE_K) ? m : EDGE_K;
    } else {
        // serial fallback (astronomically rare): lane 0 insertion top-K
        if (lane == 0) {
            float bd[EDGE_K]; int bj[EDGE_K]; int c2 = 0;
            for (int j = jstart; j < jend; ++j) {
                if (j == i) continue;
                const float4 p = pk[j];
                const float sj2 = p.x*p.x + p.y*p.y + p.z*p.z;
                const float dt  = xi*p.x + yi*p.y + zi*p.z;
                float d2 = si + sj2 - 2.0f*dt;
                d2 = fmaxf(d2, 0.0f);
                if (d2 > 25.0f) continue;
                if (c2 == EDGE_K && d2 >= bd[EDGE_K-1]) continue;
                int p2 = (c2 < EDGE_K) ? c2 : (EDGE_K - 1);
                while (p2 > 0 && bd[p2-1] > d2) { bd[p2] = bd[p2-1]; bj[p2] = bj[p2-1]; --p2; }
                bd[p2] = d2; bj[p2] = j;
                if (c2 < EDGE_K) ++c2;
            }
            for (int k = 0; k < c2; ++k) sres[k] = make_int2(__float_as_int(bd[k]), bj[k]);
        }
        cnt = (count < EDGE_K) ? count : EDGE_K;
    }
    __syncthreads();

    const int NK = n * EDGE_K;
    int* valid_out = out + 3 * NK;
    int* eb = (int*)ebuf2;
    if (lane < EDGE_K) {
        const int k = lane;
        int a = -1, b = -1, c = -1, v = 0;
        if (k < cnt) {
            const int j = sres[k].y;
            const int rj = a2r[j];
            const int rd = (rj > ri) ? (rj - ri) : (ri - rj);
            const float4 p = pk[j];
            const float dx = p.x - xi, dy = p.y - yi, dz = p.z - zi;
            const float d2s = dx*dx + dy*dy + dz*dz;
            if (rd >= 5 && d2s >= 1e-20f) { a = j; b = i; c = 0; v = 1; }
        }
        eb[3*k+0] = a;
        eb[3*k+1] = b;
        eb[3*k+2] = c;
        valid_out[i * EDGE_K + k] = v;    // 32 contiguous dwords: coalesced
    }
    __syncthreads();
    // coalesced edge write: 96 dwords as 48 contiguous int2 stores
    if (lane < 48) {
        int2* eo = (int2*)(out + 3 * (i * EDGE_K));
        eo[lane] = ebuf2[lane];
    }
    if (i == 0 && lane == 0) out[4*NK] = 1;   // the jnp.int32(1) scalar output
}

// --- fallback path (ws too small): exact round-2 structure, known-correct
__global__ __launch_bounds__(64) void spatial_edge_ref(
    const float* __restrict__ pos,
    const int* __restrict__ n2g,
    const int* __restrict__ a2r,
    int* __restrict__ out, int n)
{
    const int i = blockIdx.x;
    const int lane = threadIdx.x;
    __shared__ float sd2[CAP]; __shared__ int sj[CAP];
    __shared__ float rd2[EDGE_K]; __shared__ int rjj[EDGE_K];

    const float xi = pos[3*i+0], yi = pos[3*i+1], zi = pos[3*i+2];
    const float si = xi*xi + yi*yi + zi*zi;
    const int g = n2g[i]; const int ri = a2r[i];

    int lo = 0, hi = n;
    while (lo < hi) { int m = (lo + hi) >> 1; if (n2g[m] < g) lo = m + 1; else hi = m; }
    const int jstart = lo; hi = n;
    while (lo < hi) { int m = (lo + hi) >> 1; if (n2g[m] <= g) lo = m + 1; else hi = m; }
    const int jend = lo;

    int count = 0;
    for (int j0 = jstart; j0 < jend; j0 += 64) {
        const int j = j0 + lane;
        bool pass = false; float d2 = 0.0f;
        if (j < jend && j != i) {
            const float xj = pos[3*j+0], yj = pos[3*j+1], zj = pos[3*j+2];
            const float sj2 = xj*xj + yj*yj + zj*zj;
            const float dt  = xi*xj + yi*yj + zi*zj;
            d2 = fmaxf(si + sj2 - 2.0f*dt, 0.0f);
            pass = (d2 <= 25.0f);
        }
        const unsigned long long mask = __ballot(pass);
        if (pass) {
            const int idx = count + prefix_count(mask);
            if (idx < CAP) { sd2[idx] = d2; sj[idx] = j; }
        }
        count += __popcll(mask);
    }
    __syncthreads();

    int cnt;
    if (count <= CAP) {
        const int m = count;
        for (int c = lane; c < m; c += 64) {
            const float dc = sd2[c]; const int jc = sj[c];
            int rank = 0;
            for (int t = 0; t < m; ++t)
                rank += (sd2[t] < dc) || (sd2[t] == dc && sj[t] < jc);
            if (rank < EDGE_K) { rd2[rank] = dc; rjj[rank] = jc; }
        }
        cnt = (m < EDGE_K) ? m : EDGE_K;
    } else {
        if (lane == 0) {
            float bd[EDGE_K]; int bj[EDGE_K]; int c2 = 0;
            for (int j = jstart; j < jend; ++j) {
                if (j == i) continue;
                const float xj = pos[3*j+0], yj = pos[3*j+1], zj = pos[3*j+2];
                const float sj2 = xj*xj + yj*yj + zj*zj;
                const float dt  = xi*xj + yi*yj + zi*zj;
                float d2 = fmaxf(si + sj2 - 2.0f*dt, 0.0f);
                if (d2 > 25.0f) continue;
                if (c2 == EDGE_K && d2 >= bd[EDGE_K-1]) continue;
                int p = (c2 < EDGE_K) ? c2 : (EDGE_K - 1);
                while (p > 0 && bd[p-1] > d2) { bd[p] = bd[p-1]; bj[p] = bj[p-1]; --p; }
                bd[p] = d2; bj[p] = j;
                if (c2 < EDGE_K) ++c2;
            }
            for (int k = 0; k < c2; ++k) { rd2[k] = bd[k]; rjj[k] = bj[k]; }
        }
        cnt = (count < EDGE_K) ? count : EDGE_K;
    }
    __syncthreads();

    const int NK = n * EDGE_K;
    int* valid_out = out + 3 * NK;
    if (lane < EDGE_K) {
        const int k = lane;
        int a = -1, b = -1, c = -1, v = 0;
        if (k < cnt) {
            const int j = rjj[k];
            const int rj = a2r[j];
            const int rd = (rj > ri) ? (rj - ri) : (ri - rj);
            const float dx = pos[3*j+0] - xi, dy = pos[3*j+1] - yi, dz = pos[3*j+2] - zi;
            const float d2s = dx*dx + dy*dy + dz*dz;
            if (rd >= 5 && d2s >= 1e-20f) { a = j; b = i; c = 0; v = 1; }
        }
        const int e = i * EDGE_K + k;
        out[3*e+0] = a; out[3*e+1] = b; out[3*e+2] = c;
        valid_out[e] = v;
    }
    if (i == 0 && lane == 0) out[4*NK] = 1;
}

extern "C" void kernel_launch(void* const* d_in, const int* in_sizes, int n_in,
                              void* d_out, int out_size, void* d_ws, size_t ws_size,
                              hipStream_t stream) {
    const float* pos = (const float*)d_in[0];
    const int*   n2g = (const int*)d_in[1];
    const int*   a2r = (const int*)d_in[2];
    int* out = (int*)d_out;
    const int n = in_sizes[0] / 3;
    const size_t need = (size_t)n * sizeof(float4);
    // bit-packed ranges need js/je < 2^14; fall back to ref kernel otherwise
    const bool packed = (ws_size >= need) && (((uintptr_t)d_ws & 15) == 0)
                        && (n <= (1 << 14) - 1 + 1);   // n <= 16384
    if (packed) {
        float4* pk = (float4*)d_ws;
        hipLaunchKernelGGL(pack_kernel, dim3((n + 255) / 256), dim3(256), 0, stream,
                           pos, n2g, pk, n);
        hipLaunchKernelGGL(spatial_edge_fast, dim3(n), dim3(64), 0, stream,
                           (const float4*)pk, a2r, out, n);
    } else {
        hipLaunchKernelGGL(spatial_edge_ref, dim3(n), dim3(64), 0, stream,
                           pos, n2g, a2r, out, n);
    }
}

// Round 17
// 27.517 us; speedup vs baseline: 1.4375x; 1.0417x over previous
//
#include <hip/hip_runtime.h>

#define EDGE_K 32
#define CAP    128   // per-node candidate cap before serial fallback
#define DEPTH  8     // software-pipeline depth (chunks in flight)

__device__ __forceinline__ int prefix_count(unsigned long long mask) {
    return (int)__builtin_amdgcn_mbcnt_hi((unsigned)(mask >> 32),
                __builtin_amdgcn_mbcnt_lo((unsigned)mask, 0u));
}

// --- pack: pk[i] = (x, y, z, |p|^2), range[i] = js<<14 | je (both < 2^14).
// |p|^2 uses the textually-identical expression to the anchor's inline sj2
// (x*x + y*y + z*z -> mul, fmac, fmac) so the stored value is bit-identical
// to what the scan previously recomputed. Per-thread binary search over the
// sorted n2g is fully parallel and latency-hidden.
__global__ __launch_bounds__(256) void pack_kernel(
    const float* __restrict__ pos, const int* __restrict__ n2g,
    float4* __restrict__ pk, int* __restrict__ range, int n)
{
    int i = blockIdx.x * blockDim.x + threadIdx.x;
    if (i >= n) return;
    const float px = pos[3*i+0], py = pos[3*i+1], pz = pos[3*i+2];
    const float sq = px*px + py*py + pz*pz;
    pk[i] = make_float4(px, py, pz, sq);
    const int g = n2g[i];
    int lo = 0, hi = n;
    while (lo < hi) { int m = (lo + hi) >> 1; if (n2g[m] < g) lo = m + 1; else hi = m; }
    const int js = lo;
    hi = n;
    while (lo < hi) { int m = (lo + hi) >> 1; if (n2g[m] <= g) lo = m + 1; else hi = m; }
    const int je = lo;
    range[i] = (js << 14) | je;
}

// --- fast path: one wave per node; 3 independent prologue loads; 8-deep
// double-buffered load pipeline. Scan order, sort and epilogue are
// byte-identical to the R16 anchor; sj2 now comes from pk[j].w.
__global__ __launch_bounds__(64) void spatial_edge_fast(
    const float4* __restrict__ pk,
    const int* __restrict__ range,
    const int* __restrict__ a2r,
    int* __restrict__ out, int n)
{
    const int i    = blockIdx.x;
    const int lane = threadIdx.x;

    __shared__ int2 scand[CAP];
    __shared__ int2 sres[EDGE_K];
    __shared__ int2 ebuf2[EDGE_K * 3 / 2];   // 96 dwords, 8B-aligned

    const float4 pi = pk[i];
    const float xi = pi.x, yi = pi.y, zi = pi.z;
    const float si = xi*xi + yi*yi + zi*zi;   // same inline expr as anchor
    const int rng = range[i];                 // independent load
    const int jstart = rng >> 14;
    const int jend   = rng & 0x3FFF;
    const int ri = a2r[i];                    // independent load

    int count = 0;
    auto process = [&](float4 p, int j) {
        bool pass = false; float d2 = 0.0f;
        if (j < jend && j != i) {
            const float sj2 = p.w;            // precomputed |p_j|^2 (bit-exact)
            const float dt  = xi*p.x + yi*p.y + zi*p.z;
            d2 = si + sj2 - 2.0f*dt;          // exact reference formula
            d2 = fmaxf(d2, 0.0f);
            pass = (d2 <= 25.0f);
        }
        const unsigned long long mask = __ballot(pass);
        if (pass) {
            const int idx = count + prefix_count(mask);
            if (idx < CAP) scand[idx] = make_int2(__float_as_int(d2), j);
        }
        count += __popcll(mask);
    };

    const int nch  = (jend - jstart + 63) >> 6;
    const int jm   = jend - 1;
    const int base = jstart + lane;

    float4 buf[DEPTH];
#pragma unroll
    for (int u = 0; u < DEPTH; ++u)
        buf[u] = pk[min(base + (u << 6), jm)];          // clamped, branch-free

    for (int c = 0; c < nch; c += DEPTH) {
        // issue NEXT group's loads before processing current (double-buffer)
        float4 nxt[DEPTH];
        const int nb = base + ((c + DEPTH) << 6);
#pragma unroll
        for (int u = 0; u < DEPTH; ++u)
            nxt[u] = pk[min(nb + (u << 6), jm)];        // clamped: safe over-read
        const int ja = jstart + (c << 6) + lane;
#pragma unroll
        for (int u = 0; u < DEPTH; ++u) {
            if (c + u < nch) process(buf[u], ja + (u << 6));
        }
#pragma unroll
        for (int u = 0; u < DEPTH; ++u) buf[u] = nxt[u];
    }
    __syncthreads();

    int cnt = 0;
    if (count <= CAP) {
        // rank-based stable sort: rank = #{(d2',j') < (d2,j)} lexicographic
        const int m = count;
        for (int c = lane; c < m; c += 64) {
            const int2 e = scand[c];
            const float dc = __int_as_float(e.x);
            int rank = 0;
            for (int t = 0; t < m; ++t) {
                const int2 et = scand[t];
                const float dtv = __int_as_float(et.x);
                rank += (dtv < dc) || (dtv == dc && et.y < e.y);
            }
            if (rank < EDGE_K) sres[rank] = e;
        }
        cnt = (m < EDGE_K) ? m : EDGE_K;
    } else {
        // serial fallback (astronomically rare): lane 0 insertion top-K
        if (lane == 0) {
            float bd[EDGE_K]; int bj[EDGE_K]; int c2 = 0;
            for (int j = jstart; j < jend; ++j) {
                if (j == i) continue;
                const float4 p = pk[j];
                const float sj2 = p.w;
                const float dt  = xi*p.x + yi*p.y + zi*p.z;
                float d2 = si + sj2 - 2.0f*dt;
                d2 = fmaxf(d2, 0.0f);
                if (d2 > 25.0f) continue;
                if (c2 == EDGE_K && d2 >= bd[EDGE_K-1]) continue;
                int p2 = (c2 < EDGE_K) ? c2 : (EDGE_K - 1);
                while (p2 > 0 && bd[p2-1] > d2) { bd[p2] = bd[p2-1]; bj[p2] = bj[p2-1]; --p2; }
                bd[p2] = d2; bj[p2] = j;
                if (c2 < EDGE_K) ++c2;
            }
            for (int k = 0; k < c2; ++k) sres[k] = make_int2(__float_as_int(bd[k]), bj[k]);
        }
        cnt = (count < EDGE_K) ? count : EDGE_K;
    }
    __syncthreads();

    const int NK = n * EDGE_K;
    int* valid_out = out + 3 * NK;
    int* eb = (int*)ebuf2;
    if (lane < EDGE_K) {
        const int k = lane;
        int a = -1, b = -1, c = -1, v = 0;
        if (k < cnt) {
            const int j = sres[k].y;
            const int rj = a2r[j];
            const int rd = (rj > ri) ? (rj - ri) : (ri - rj);
            const float4 p = pk[j];
            const float dx = p.x - xi, dy = p.y - yi, dz = p.z - zi;
            const float d2s = dx*dx + dy*dy + dz*dz;
            if (rd >= 5 && d2s >= 1e-20f) { a = j; b = i; c = 0; v = 1; }
        }
        eb[3*k+0] = a;
        eb[3*k+1] = b;
        eb[3*k+2] = c;
        valid_out[i * EDGE_K + k] = v;    // 32 contiguous dwords: coalesced
    }
    __syncthreads();
    // coalesced edge write: 96 dwords as 48 contiguous int2 stores
    if (lane < 48) {
        int2* eo = (int2*)(out + 3 * (i * EDGE_K));
        eo[lane] = ebuf2[lane];
    }
    if (i == 0 && lane == 0) out[4*NK] = 1;   // the jnp.int32(1) scalar output
}

// --- fallback path (ws too small): exact round-2 structure, known-correct
__global__ __launch_bounds__(64) void spatial_edge_ref(
    const float* __restrict__ pos,
    const int* __restrict__ n2g,
    const int* __restrict__ a2r,
    int* __restrict__ out, int n)
{
    const int i = blockIdx.x;
    const int lane = threadIdx.x;
    __shared__ float sd2[CAP]; __shared__ int sj[CAP];
    __shared__ float rd2[EDGE_K]; __shared__ int rjj[EDGE_K];

    const float xi = pos[3*i+0], yi = pos[3*i+1], zi = pos[3*i+2];
    const float si = xi*xi + yi*yi + zi*zi;
    const int g = n2g[i]; const int ri = a2r[i];

    int lo = 0, hi = n;
    while (lo < hi) { int m = (lo + hi) >> 1; if (n2g[m] < g) lo = m + 1; else hi = m; }
    const int jstart = lo; hi = n;
    while (lo < hi) { int m = (lo + hi) >> 1; if (n2g[m] <= g) lo = m + 1; else hi = m; }
    const int jend = lo;

    int count = 0;
    for (int j0 = jstart; j0 < jend; j0 += 64) {
        const int j = j0 + lane;
        bool pass = false; float d2 = 0.0f;
        if (j < jend && j != i) {
            const float xj = pos[3*j+0], yj = pos[3*j+1], zj = pos[3*j+2];
            const float sj2 = xj*xj + yj*yj + zj*zj;
            const float dt  = xi*xj + yi*yj + zi*zj;
            d2 = fmaxf(si + sj2 - 2.0f*dt, 0.0f);
            pass = (d2 <= 25.0f);
        }
        const unsigned long long mask = __ballot(pass);
        if (pass) {
            const int idx = count + prefix_count(mask);
            if (idx < CAP) { sd2[idx] = d2; sj[idx] = j; }
        }
        count += __popcll(mask);
    }
    __syncthreads();

    int cnt;
    if (count <= CAP) {
        const int m = count;
        for (int c = lane; c < m; c += 64) {
            const float dc = sd2[c]; const int jc = sj[c];
            int rank = 0;
            for (int t = 0; t < m; ++t)
                rank += (sd2[t] < dc) || (sd2[t] == dc && sj[t] < jc);
            if (rank < EDGE_K) { rd2[rank] = dc; rjj[rank] = jc; }
        }
        cnt = (m < EDGE_K) ? m : EDGE_K;
    } else {
        if (lane == 0) {
            float bd[EDGE_K]; int bj[EDGE_K]; int c2 = 0;
            for (int j = jstart; j < jend; ++j) {
                if (j == i) continue;
                const float xj = pos[3*j+0], yj = pos[3*j+1], zj = pos[3*j+2];
                const float sj2 = xj*xj + yj*yj + zj*zj;
                const float dt  = xi*xj + yi*yj + zi*zj;
                float d2 = fmaxf(si + sj2 - 2.0f*dt, 0.0f);
                if (d2 > 25.0f) continue;
                if (c2 == EDGE_K && d2 >= bd[EDGE_K-1]) continue;
                int p = (c2 < EDGE_K) ? c2 : (EDGE_K - 1);
                while (p > 0 && bd[p-1] > d2) { bd[p] = bd[p-1]; bj[p] = bj[p-1]; --p; }
                bd[p] = d2; bj[p] = j;
                if (c2 < EDGE_K) ++c2;
            }
            for (int k = 0; k < c2; ++k) { rd2[k] = bd[k]; rjj[k] = bj[k]; }
        }
        cnt = (count < EDGE_K) ? count : EDGE_K;
    }
    __syncthreads();

    const int NK = n * EDGE_K;
    int* valid_out = out + 3 * NK;
    if (lane < EDGE_K) {
        const int k = lane;
        int a = -1, b = -1, c = -1, v = 0;
        if (k < cnt) {
            const int j = rjj[k];
            const int rj = a2r[j];
            const int rd = (rj > ri) ? (rj - ri) : (ri - rj);
            const float dx = pos[3*j+0] - xi, dy = pos[3*j+1] - yi, dz = pos[3*j+2] - zi;
            const float d2s = dx*dx + dy*dy + dz*dz;
            if (rd >= 5 && d2s >= 1e-20f) { a = j; b = i; c = 0; v = 1; }
        }
        const int e = i * EDGE_K + k;
        out[3*e+0] = a; out[3*e+1] = b; out[3*e+2] = c;
        valid_out[e] = v;
    }
    if (i == 0 && lane == 0) out[4*NK] = 1;
}

extern "C" void kernel_launch(void* const* d_in, const int* in_sizes, int n_in,
                              void* d_out, int out_size, void* d_ws, size_t ws_size,
                              hipStream_t stream) {
    const float* pos = (const float*)d_in[0];
    const int*   n2g = (const int*)d_in[1];
    const int*   a2r = (const int*)d_in[2];
    int* out = (int*)d_out;
    const int n = in_sizes[0] / 3;
    const size_t need = (size_t)n * sizeof(float4) + (size_t)n * sizeof(int);
    // bit-packed ranges need js/je <= 2^14; fall back to ref kernel otherwise
    const bool packed = (ws_size >= need) && (((uintptr_t)d_ws & 15) == 0)
                        && (n <= (1 << 14));
    if (packed) {
        float4* pk  = (float4*)d_ws;
        int* range  = (int*)(pk + n);
        hipLaunchKernelGGL(pack_kernel, dim3((n + 255) / 256), dim3(256), 0, stream,
                           pos, n2g, pk, range, n);
        hipLaunchKernelGGL(spatial_edge_fast, dim3(n), dim3(64), 0, stream,
                           (const float4*)pk, (const int*)range, a2r, out, n);
    } else {
        hipLaunchKernelGGL(spatial_edge_ref, dim3(n), dim3(64), 0, stream,
                           pos, n2g, a2r, out, n);
    }
}